// Round 12
// baseline (199.384 us; speedup 1.0000x reference)
//
#include <hip/hip_runtime.h>

using half8 = __attribute__((ext_vector_type(8))) _Float16;
using f32x4 = __attribute__((ext_vector_type(4))) float;

#define Lc 4096
#define Ec 64
#define Mc 64
#define BHc 128

// 2*pi/4096
#define TWO_PI_OVER_L 1.5339807878856412e-3f

// ---------------------------------------------------------------------------
// Twiddle tables, both coalesced:
//   Tt[m2][l]  f16, m2 in [0,128): rows 0..63 = cos(th), rows 64..127 = -sin(th)
//   UL[l][m2]  f16: cols 0..63 = cos(th), cols 64..127 = +sin(th)
// th = 2*pi*k_m*l/L
// ---------------------------------------------------------------------------
__global__ __launch_bounds__(256) void twid_k(const int* __restrict__ idx,
                                              _Float16* __restrict__ Tt,
                                              _Float16* __restrict__ UL) {
    int id = blockIdx.x * 256 + threadIdx.x;   // 0 .. 524287
    {   // UL pass: l = id>>7, m2 = id&127  (coalesced in m2)
        int l = id >> 7, m2 = id & 127, m = m2 & 63;
        int k = idx[m];
        int ph = (k * l) & (Lc - 1);
        float s, c;
        sincosf((float)ph * TWO_PI_OVER_L, &s, &c);
        UL[id] = (_Float16)((m2 >= 64) ? s : c);
    }
    {   // Tt pass: m2 = id>>12, l = id&4095  (coalesced in l)
        int m2 = id >> 12, l = id & 4095, m = m2 & 63;
        int k = idx[m];
        int ph = (k * l) & (Lc - 1);
        float s, c;
        sincosf((float)ph * TWO_PI_OVER_L, &s, &c);
        Tt[id] = (_Float16)((m2 >= 64) ? -s : c);
    }
}

// ---------------------------------------------------------------------------
// Forward: selP[ch][bh][m2=128][e=64] = sum_{l in chunk} Tt[m2][l] * x[bh][l][e]
// grid (BHc, NCH), 256 thr (4 waves). Wave w owns m2 rows [32w, 32w+32).
// r8 pipeline: double-buffered LDS (1 barrier/tile) + 2-tile-ahead register
// prefetch with two register sets. Measured (r11 probe): ~30 us, near floor.
// xs layout: [e][l] f16, row = 128B, byte ^= ((e&7)<<4).
// ---------------------------------------------------------------------------
#define LOADT(SET, S) do{                                                     \
    const float* g0_ = xp + (size_t)((S) * 64 + 2 * lp) * Ec;                 \
    const float* g1_ = xp + (size_t)((S) * 64 + 2 * lp + 32) * Ec;            \
    ra[SET][0] = *(const float4*)g0_;  rb[SET][0] = *(const float4*)(g0_ + Ec);\
    ra[SET][1] = *(const float4*)g1_;  rb[SET][1] = *(const float4*)(g1_ + Ec);\
}while(0)

#define PACKT(SET, BUF) do{                                                   \
    _Pragma("unroll")                                                         \
    for (int i_ = 0; i_ < 2; ++i_) {                                          \
        const float* pa_ = (const float*)&ra[SET][i_];                        \
        const float* pb_ = (const float*)&rb[SET][i_];                        \
        unsigned int pk_[4];                                                  \
        _Pragma("unroll")                                                     \
        for (int j_ = 0; j_ < 4; ++j_) {                                      \
            unsigned short ua_ = __builtin_bit_cast(unsigned short, (_Float16)pa_[j_]); \
            unsigned short ub_ = __builtin_bit_cast(unsigned short, (_Float16)pb_[j_]); \
            pk_[j_] = ua_ | ((unsigned int)ub_ << 16);                        \
        }                                                                     \
        _Pragma("unroll")                                                     \
        for (int j_ = 0; j_ < 4; ++j_) {                                      \
            int jr_ = (j_ + col4) & 3;                                        \
            int e_  = col4 * 4 + jr_;                                         \
            int byt_ = (e_ * 128 + lp * 4 + i_ * 64) ^ ((e_ & 7) << 4);       \
            *(unsigned int*)((char*)xs[BUF] + byt_) = pk_[jr_];               \
        }                                                                     \
    }                                                                         \
}while(0)

#define MFMA_STEP(S, BUF) do{                                                 \
    _Pragma("unroll")                                                         \
    for (int ks_ = 0; ks_ < 2; ++ks_) {                                       \
        half8 A0_ = *(const half8*)(tp + (S) * 64 + ks_ * 32);                \
        half8 A1_ = *(const half8*)(tp + (size_t)16 * Lc + (S) * 64 + ks_ * 32); \
        _Pragma("unroll")                                                     \
        for (int j_ = 0; j_ < 4; ++j_) {                                      \
            int rbyt_ = ((16 * j_ + lo16) * 128 + ks_ * 64 + kg * 16) ^ ((lo16 & 7) << 4); \
            half8 Bv_ = *(const half8*)((const char*)xs[BUF] + rbyt_);        \
            acc[0][j_] = __builtin_amdgcn_mfma_f32_16x16x32_f16(A0_, Bv_, acc[0][j_], 0, 0, 0); \
            acc[1][j_] = __builtin_amdgcn_mfma_f32_16x16x32_f16(A1_, Bv_, acc[1][j_], 0, 0, 0); \
        }                                                                     \
    }                                                                         \
}while(0)

template<int NCH>
__global__ __launch_bounds__(256) void fwd_k(const float* __restrict__ x,
                                             const _Float16* __restrict__ Tt,
                                             float* __restrict__ selP) {
    constexpr int CH = Lc / NCH;
    constexpr int NT = CH / 64;                // 8 at NCH=8 (even)
    __shared__ _Float16 xs[2][64 * 64];        // 2 x 8KB
    int bh = blockIdx.x, ch = blockIdx.y;
    int tid = threadIdx.x;
    int lane = tid & 63, w = tid >> 6;
    int lo16 = lane & 15, kg = lane >> 4;
    int col4 = tid & 15, lp = tid >> 4;        // staging: e4=col4*4, row-pair lp

    const float* xp = x + ((size_t)bh * Lc + (size_t)ch * CH) * Ec + col4 * 4;
    const _Float16* tp = Tt + (size_t)(w * 32 + lo16) * Lc + ch * CH + kg * 8;

    float4 ra[2][2], rb[2][2];                 // [regset][i]
    LOADT(0, 0);                               // tile 0 -> set0
    LOADT(1, 1);                               // tile 1 -> set1
    PACKT(0, 0);                               // tile 0 -> buf0
    __syncthreads();

    f32x4 acc[2][4] = {};
    for (int t = 0; t < NT / 2; ++t) {
        int s0 = 2 * t, s1 = 2 * t + 1;
        // ---- even tile: compute buf0 (tile s0), fill buf1 (tile s0+1) ----
        if (s0 + 2 < NT) LOADT(0, s0 + 2);     // tile s0+2 -> set0 (free)
        PACKT(1, 1);                           // tile s0+1 (set1) -> buf1
        MFMA_STEP(s0, 0);
        __syncthreads();
        // ---- odd tile: compute buf1 (tile s1), fill buf0 (tile s1+1) ----
        if (s1 + 2 < NT) LOADT(1, s1 + 2);     // tile s1+2 -> set1 (free)
        if (s1 + 1 < NT) PACKT(0, 0);          // tile s1+1 (set0) -> buf0
        MFMA_STEP(s1, 1);
        __syncthreads();
    }

    float* op = selP + (size_t)(ch * BHc + bh) * (128 * Ec);
    #pragma unroll
    for (int a = 0; a < 2; ++a)
        #pragma unroll
        for (int j = 0; j < 4; ++j)
            #pragma unroll
            for (int r = 0; r < 4; ++r) {
                int m2 = w * 32 + a * 16 + kg * 4 + r;
                int e  = 16 * j + lo16;
                op[m2 * Ec + e] = acc[a][j][r];
            }
}

// ---------------------------------------------------------------------------
// Mix v2: reduce K-partials, apply complex weight einsum, fold irfft scale.
// Vt[bh][o=64][m2=128] f16: cols 0..63 = s*Re(out_sel), 64..127 = -s*Im(out_sel)
// grid (BHc, 2 oh, 2 mh) = 512 blocks, stage 64 selP rows (16.6KB), unroll 8.
// r12: LAUNCHED TWICE (probe).
// ---------------------------------------------------------------------------
__global__ __launch_bounds__(256) void mix_k(const float* __restrict__ selP,
                                             const float* __restrict__ wgt,
                                             const int* __restrict__ idx,
                                             _Float16* __restrict__ Vt, int nch) {
    __shared__ float sel_s[64 * 65];           // rows 0..31 Re, 32..63 Im; 16.6KB
    int bh = blockIdx.x, oh = blockIdx.y, mh = blockIdx.z;
    int tid = threadIdx.x;
    #pragma unroll
    for (int i = 0; i < 4; ++i) {
        int f4 = i * 256 + tid;                // 1024 float4 = 64 rows x 64 e
        int lr = f4 >> 4, e4 = (f4 & 15) * 4;
        int m2 = (lr < 32) ? (mh * 32 + lr) : (64 + mh * 32 + (lr - 32));
        float4 a = make_float4(0.f, 0.f, 0.f, 0.f);
        for (int chn = 0; chn < nch; ++chn) {
            float4 v = *(const float4*)(selP + (size_t)(chn * BHc + bh) * 8192
                                             + (size_t)m2 * Ec + e4);
            a.x += v.x; a.y += v.y; a.z += v.z; a.w += v.w;
        }
        float* dst = &sel_s[lr * 65 + e4];
        dst[0] = a.x; dst[1] = a.y; dst[2] = a.z; dst[3] = a.w;
    }
    __syncthreads();
    int og = tid & 15, mg = tid >> 4;
    int o0 = oh * 32 + og * 2;                 // 2 o per thread
    int m0 = mh * 32 + mg * 2;                 // 2 m per thread (global m)
    int lm = mg * 2;                           // local Re row
    float rR[2][2] = {{0}}, rI[2][2] = {{0}};
    #pragma unroll 8
    for (int e = 0; e < Ec; ++e) {
        float sr0 = sel_s[lm * 65 + e];
        float sr1 = sel_s[(lm + 1) * 65 + e];
        float si0 = sel_s[(32 + lm) * 65 + e];
        float si1 = sel_s[(32 + lm + 1) * 65 + e];
        #pragma unroll
        for (int i = 0; i < 2; ++i) {
            const float4* wp = (const float4*)&wgt[(((size_t)e * Ec + (o0 + i)) * Mc + m0) * 2];
            float4 wv = *wp;   // wR[m0], wI[m0], wR[m0+1], wI[m0+1]
            rR[i][0] += sr0 * wv.x - si0 * wv.y;
            rI[i][0] += sr0 * wv.y + si0 * wv.x;
            rR[i][1] += sr1 * wv.z - si1 * wv.w;
            rI[i][1] += sr1 * wv.w + si1 * wv.z;
        }
    }
    float s0 = (idx[m0] == 0 ? 1.0f : 2.0f) / (float)Lc;
    float s1 = (idx[m0 + 1] == 0 ? 1.0f : 2.0f) / (float)Lc;
    #pragma unroll
    for (int i = 0; i < 2; ++i) {
        _Float16* vp = Vt + ((size_t)bh * 64 + o0 + i) * 128;
        unsigned short r0 = __builtin_bit_cast(unsigned short, (_Float16)(rR[i][0] * s0));
        unsigned short r1 = __builtin_bit_cast(unsigned short, (_Float16)(rR[i][1] * s1));
        unsigned short i0 = __builtin_bit_cast(unsigned short, (_Float16)(-rI[i][0] * s0));
        unsigned short i1 = __builtin_bit_cast(unsigned short, (_Float16)(-rI[i][1] * s1));
        *(unsigned int*)&vp[m0]      = r0 | ((unsigned int)r1 << 16);
        *(unsigned int*)&vp[64 + m0] = i0 | ((unsigned int)i1 << 16);
    }
}

// ---------------------------------------------------------------------------
// Inverse: out[bh][l][o] = sum_{m2} UL[l][m2] * V[m2][o]
// grid (BHc, 16), 256 thr. Wave w owns l rows [64w, 64w+64) of a 256-l block.
// Vt staged in LDS [o][136] (17-bank stride).
// r12: LAUNCHED TWICE (probe).
// ---------------------------------------------------------------------------
__global__ __launch_bounds__(256) void inv_k(const _Float16* __restrict__ UL,
                                             const _Float16* __restrict__ Vt,
                                             float* __restrict__ out) {
    __shared__ _Float16 vs[64 * 136];          // 17.4KB
    int bh = blockIdx.x, lb = blockIdx.y;
    int tid = threadIdx.x, lane = tid & 63, w = tid >> 6;
    int lo16 = lane & 15, kg = lane >> 4;
    #pragma unroll
    for (int i = 0; i < 4; ++i) {
        int f = i * 256 + tid;                 // 1024 chunks of 8 f16
        int row = f >> 4, seg = f & 15;
        uint4 t4 = *(const uint4*)(Vt + (size_t)bh * 8192 + row * 128 + seg * 8);
        *(uint4*)&vs[row * 136 + seg * 8] = t4;
    }
    __syncthreads();
    int lt0 = lb * 256 + w * 64;
    const _Float16* up = UL + (size_t)(lt0 + lo16) * 128 + kg * 8;
    f32x4 acc[4][4] = {};
    #pragma unroll
    for (int ks = 0; ks < 4; ++ks) {
        half8 Af[4];
        #pragma unroll
        for (int a = 0; a < 4; ++a)
            Af[a] = *(const half8*)(up + (size_t)a * 16 * 128 + ks * 32);
        #pragma unroll
        for (int j = 0; j < 4; ++j) {
            half8 Bf = *(const half8*)&vs[(16 * j + lo16) * 136 + ks * 32 + kg * 8];
            #pragma unroll
            for (int a = 0; a < 4; ++a)
                acc[a][j] = __builtin_amdgcn_mfma_f32_16x16x32_f16(Af[a], Bf, acc[a][j], 0, 0, 0);
        }
    }
    float* op = out + ((size_t)bh * Lc + lt0) * Ec;
    #pragma unroll
    for (int a = 0; a < 4; ++a)
        #pragma unroll
        for (int j = 0; j < 4; ++j)
            #pragma unroll
            for (int r = 0; r < 4; ++r) {
                int ll = a * 16 + kg * 4 + r;
                int o  = 16 * j + lo16;
                op[ll * Ec + o] = acc[a][j][r];
            }
}

// ---------------------------------------------------------------------------
extern "C" void kernel_launch(void* const* d_in, const int* in_sizes, int n_in,
                              void* d_out, int out_size, void* d_ws, size_t ws_size,
                              hipStream_t stream) {
    const float* x   = (const float*)d_in[0];
    const float* wgt = (const float*)d_in[1];
    const int*   idx = (const int*)d_in[2];
    float* out = (float*)d_out;

    // workspace layout: selP (nch*4MB) | Tt (1MB) | UL (1MB) | Vt (2MB)
    size_t need8 = (size_t)8 * BHc * 8192 * 4 + (2ull * 128 * Lc + (size_t)BHc * 8192) * 2;
    int nch = (ws_size >= need8) ? 8 : 4;

    char* ws = (char*)d_ws;
    float*    selP = (float*)ws;
    _Float16* Tt   = (_Float16*)(ws + (size_t)nch * BHc * 8192 * 4);
    _Float16* UL   = Tt + (size_t)128 * Lc;
    _Float16* Vt   = UL + (size_t)Lc * 128;

    // r12 PROBE: twid, mix, inv each launched twice (all idempotent).
    // Δdur vs r10 (123.0) = twid + mix + inv (+3 boundary gaps).
    twid_k<<<2048, 256, 0, stream>>>(idx, Tt, UL);
    twid_k<<<2048, 256, 0, stream>>>(idx, Tt, UL);
    if (nch == 8)
        fwd_k<8><<<dim3(BHc, 8), 256, 0, stream>>>(x, Tt, selP);
    else
        fwd_k<4><<<dim3(BHc, 4), 256, 0, stream>>>(x, Tt, selP);
    mix_k<<<dim3(BHc, 2, 2), 256, 0, stream>>>(selP, wgt, idx, Vt, nch);
    mix_k<<<dim3(BHc, 2, 2), 256, 0, stream>>>(selP, wgt, idx, Vt, nch);
    inv_k<<<dim3(BHc, 16), 256, 0, stream>>>(UL, Vt, out);
    inv_k<<<dim3(BHc, 16), 256, 0, stream>>>(UL, Vt, out);
}

// Round 13
// 130.654 us; speedup vs baseline: 1.5260x; 1.5260x over previous
//
#include <hip/hip_runtime.h>

using half8 = __attribute__((ext_vector_type(8))) _Float16;
using f32x4 = __attribute__((ext_vector_type(4))) float;

#define Lc 4096
#define Ec 64
#define Mc 64
#define BHc 128

// 2*pi/4096
#define TWO_PI_OVER_L 1.5339807878856412e-3f

// ---------------------------------------------------------------------------
// Twiddle tables, both coalesced. r13: native __sinf/__cosf (v_sin/v_cos) —
// accuracy ~2^-21, far below f16 storage quantization (2^-11).
//   Tt[m2][l]  f16, m2 in [0,128): rows 0..63 = cos(th), rows 64..127 = -sin(th)
//   UL[l][m2]  f16: cols 0..63 = cos(th), cols 64..127 = +sin(th)
// ---------------------------------------------------------------------------
__global__ __launch_bounds__(256) void twid_k(const int* __restrict__ idx,
                                              _Float16* __restrict__ Tt,
                                              _Float16* __restrict__ UL) {
    int id = blockIdx.x * 256 + threadIdx.x;   // 0 .. 524287
    {   // UL pass: l = id>>7, m2 = id&127  (coalesced in m2)
        int l = id >> 7, m2 = id & 127, m = m2 & 63;
        int k = idx[m];
        int ph = (k * l) & (Lc - 1);
        float ang = (float)ph * TWO_PI_OVER_L;
        UL[id] = (_Float16)((m2 >= 64) ? __sinf(ang) : __cosf(ang));
    }
    {   // Tt pass: m2 = id>>12, l = id&4095  (coalesced in l)
        int m2 = id >> 12, l = id & 4095, m = m2 & 63;
        int k = idx[m];
        int ph = (k * l) & (Lc - 1);
        float ang = (float)ph * TWO_PI_OVER_L;
        Tt[id] = (_Float16)((m2 >= 64) ? -__sinf(ang) : __cosf(ang));
    }
}

// ---------------------------------------------------------------------------
// Forward: selP[ch][bh][m2=128][e=64] = sum_{l in chunk} Tt[m2][l] * x[bh][l][e]
// grid (BHc, NCH), 256 thr (4 waves). Wave w owns m2 rows [32w, 32w+32).
// r8 pipeline: double-buffered LDS (1 barrier/tile) + 2-tile-ahead register
// prefetch. Measured (r11 probe): ~30 us ≈ traffic floor. UNCHANGED.
// xs layout: [e][l] f16, row = 128B, byte ^= ((e&7)<<4).
// ---------------------------------------------------------------------------
#define LOADT(SET, S) do{                                                     \
    const float* g0_ = xp + (size_t)((S) * 64 + 2 * lp) * Ec;                 \
    const float* g1_ = xp + (size_t)((S) * 64 + 2 * lp + 32) * Ec;            \
    ra[SET][0] = *(const float4*)g0_;  rb[SET][0] = *(const float4*)(g0_ + Ec);\
    ra[SET][1] = *(const float4*)g1_;  rb[SET][1] = *(const float4*)(g1_ + Ec);\
}while(0)

#define PACKT(SET, BUF) do{                                                   \
    _Pragma("unroll")                                                         \
    for (int i_ = 0; i_ < 2; ++i_) {                                          \
        const float* pa_ = (const float*)&ra[SET][i_];                        \
        const float* pb_ = (const float*)&rb[SET][i_];                        \
        unsigned int pk_[4];                                                  \
        _Pragma("unroll")                                                     \
        for (int j_ = 0; j_ < 4; ++j_) {                                      \
            unsigned short ua_ = __builtin_bit_cast(unsigned short, (_Float16)pa_[j_]); \
            unsigned short ub_ = __builtin_bit_cast(unsigned short, (_Float16)pb_[j_]); \
            pk_[j_] = ua_ | ((unsigned int)ub_ << 16);                        \
        }                                                                     \
        _Pragma("unroll")                                                     \
        for (int j_ = 0; j_ < 4; ++j_) {                                      \
            int jr_ = (j_ + col4) & 3;                                        \
            int e_  = col4 * 4 + jr_;                                         \
            int byt_ = (e_ * 128 + lp * 4 + i_ * 64) ^ ((e_ & 7) << 4);       \
            *(unsigned int*)((char*)xs[BUF] + byt_) = pk_[jr_];               \
        }                                                                     \
    }                                                                         \
}while(0)

#define MFMA_STEP(S, BUF) do{                                                 \
    _Pragma("unroll")                                                         \
    for (int ks_ = 0; ks_ < 2; ++ks_) {                                       \
        half8 A0_ = *(const half8*)(tp + (S) * 64 + ks_ * 32);                \
        half8 A1_ = *(const half8*)(tp + (size_t)16 * Lc + (S) * 64 + ks_ * 32); \
        _Pragma("unroll")                                                     \
        for (int j_ = 0; j_ < 4; ++j_) {                                      \
            int rbyt_ = ((16 * j_ + lo16) * 128 + ks_ * 64 + kg * 16) ^ ((lo16 & 7) << 4); \
            half8 Bv_ = *(const half8*)((const char*)xs[BUF] + rbyt_);        \
            acc[0][j_] = __builtin_amdgcn_mfma_f32_16x16x32_f16(A0_, Bv_, acc[0][j_], 0, 0, 0); \
            acc[1][j_] = __builtin_amdgcn_mfma_f32_16x16x32_f16(A1_, Bv_, acc[1][j_], 0, 0, 0); \
        }                                                                     \
    }                                                                         \
}while(0)

template<int NCH>
__global__ __launch_bounds__(256) void fwd_k(const float* __restrict__ x,
                                             const _Float16* __restrict__ Tt,
                                             float* __restrict__ selP) {
    constexpr int CH = Lc / NCH;
    constexpr int NT = CH / 64;                // 8 at NCH=8 (even)
    __shared__ _Float16 xs[2][64 * 64];        // 2 x 8KB
    int bh = blockIdx.x, ch = blockIdx.y;
    int tid = threadIdx.x;
    int lane = tid & 63, w = tid >> 6;
    int lo16 = lane & 15, kg = lane >> 4;
    int col4 = tid & 15, lp = tid >> 4;        // staging: e4=col4*4, row-pair lp

    const float* xp = x + ((size_t)bh * Lc + (size_t)ch * CH) * Ec + col4 * 4;
    const _Float16* tp = Tt + (size_t)(w * 32 + lo16) * Lc + ch * CH + kg * 8;

    float4 ra[2][2], rb[2][2];                 // [regset][i]
    LOADT(0, 0);                               // tile 0 -> set0
    LOADT(1, 1);                               // tile 1 -> set1
    PACKT(0, 0);                               // tile 0 -> buf0
    __syncthreads();

    f32x4 acc[2][4] = {};
    for (int t = 0; t < NT / 2; ++t) {
        int s0 = 2 * t, s1 = 2 * t + 1;
        if (s0 + 2 < NT) LOADT(0, s0 + 2);
        PACKT(1, 1);
        MFMA_STEP(s0, 0);
        __syncthreads();
        if (s1 + 2 < NT) LOADT(1, s1 + 2);
        if (s1 + 1 < NT) PACKT(0, 0);
        MFMA_STEP(s1, 1);
        __syncthreads();
    }

    float* op = selP + (size_t)(ch * BHc + bh) * (128 * Ec);
    #pragma unroll
    for (int a = 0; a < 2; ++a)
        #pragma unroll
        for (int j = 0; j < 4; ++j)
            #pragma unroll
            for (int r = 0; r < 4; ++r) {
                int m2 = w * 32 + a * 16 + kg * 4 + r;
                int e  = 16 * j + lo16;
                op[m2 * Ec + e] = acc[a][j][r];
            }
}

// ---------------------------------------------------------------------------
// Mix v3: reduce K-partials, complex weight einsum, fold irfft scale.
// r13: grid (BHc, 4 mh) — split by m ONLY, so selP is read exactly once
// (was 2x with the oh split). Block: all 64 o x 16 m. Wave w = m-group ->
// sel_s reads are wave-uniform broadcasts (free). e-loop unrolled x4.
// Vt[bh][o=64][m2=128] f16: cols 0..63 = s*Re, 64..127 = -s*Im.
// ---------------------------------------------------------------------------
__global__ __launch_bounds__(256) void mix_k(const float* __restrict__ selP,
                                             const float* __restrict__ wgt,
                                             const int* __restrict__ idx,
                                             _Float16* __restrict__ Vt, int nch) {
    __shared__ float sel_s[32 * 65];           // 16 Re rows + 16 Im rows; 8.3KB
    int bh = blockIdx.x, mh = blockIdx.y;      // mh 0..3
    int tid = threadIdx.x;
    #pragma unroll
    for (int i = 0; i < 2; ++i) {
        int f4 = i * 256 + tid;                // 512 float4 = 32 rows x 64 e
        int lr = f4 >> 4, e4 = (f4 & 15) * 4;
        int m2 = (lr < 16) ? (mh * 16 + lr) : (64 + mh * 16 + (lr - 16));
        float4 a = make_float4(0.f, 0.f, 0.f, 0.f);
        for (int chn = 0; chn < nch; ++chn) {
            float4 v = *(const float4*)(selP + (size_t)(chn * BHc + bh) * 8192
                                             + (size_t)m2 * Ec + e4);
            a.x += v.x; a.y += v.y; a.z += v.z; a.w += v.w;
        }
        float* dst = &sel_s[lr * 65 + e4];
        dst[0] = a.x; dst[1] = a.y; dst[2] = a.z; dst[3] = a.w;
    }
    __syncthreads();
    int o = tid & 63, mg = tid >> 6;           // wave = m-group
    int mloc = mg * 4;                         // local m base (4 m per thread)
    int m0 = mh * 16 + mloc;                   // global m base
    float rR[4] = {0}, rI[4] = {0};
    #pragma unroll 4
    for (int e = 0; e < Ec; ++e) {
        const float4* wp = (const float4*)&wgt[(((size_t)e * Ec + o) * Mc + m0) * 2];
        float4 w0 = wp[0], w1 = wp[1];         // (R,I) for m0..m0+3
        float sr0 = sel_s[(mloc + 0) * 65 + e], si0 = sel_s[(16 + mloc + 0) * 65 + e];
        float sr1 = sel_s[(mloc + 1) * 65 + e], si1 = sel_s[(16 + mloc + 1) * 65 + e];
        float sr2 = sel_s[(mloc + 2) * 65 + e], si2 = sel_s[(16 + mloc + 2) * 65 + e];
        float sr3 = sel_s[(mloc + 3) * 65 + e], si3 = sel_s[(16 + mloc + 3) * 65 + e];
        rR[0] += sr0 * w0.x - si0 * w0.y;  rI[0] += sr0 * w0.y + si0 * w0.x;
        rR[1] += sr1 * w0.z - si1 * w0.w;  rI[1] += sr1 * w0.w + si1 * w0.z;
        rR[2] += sr2 * w1.x - si2 * w1.y;  rI[2] += sr2 * w1.y + si2 * w1.x;
        rR[3] += sr3 * w1.z - si3 * w1.w;  rI[3] += sr3 * w1.w + si3 * w1.z;
    }
    _Float16* vp = Vt + ((size_t)bh * 64 + o) * 128;
    #pragma unroll
    for (int p = 0; p < 2; ++p) {
        float s0 = (idx[m0 + 2 * p] == 0 ? 1.0f : 2.0f) / (float)Lc;
        float s1 = (idx[m0 + 2 * p + 1] == 0 ? 1.0f : 2.0f) / (float)Lc;
        unsigned short r0 = __builtin_bit_cast(unsigned short, (_Float16)(rR[2 * p] * s0));
        unsigned short r1 = __builtin_bit_cast(unsigned short, (_Float16)(rR[2 * p + 1] * s1));
        unsigned short i0 = __builtin_bit_cast(unsigned short, (_Float16)(-rI[2 * p] * s0));
        unsigned short i1 = __builtin_bit_cast(unsigned short, (_Float16)(-rI[2 * p + 1] * s1));
        *(unsigned int*)&vp[m0 + 2 * p]      = r0 | ((unsigned int)r1 << 16);
        *(unsigned int*)&vp[64 + m0 + 2 * p] = i0 | ((unsigned int)i1 << 16);
    }
}

// ---------------------------------------------------------------------------
// Inverse: out[bh][l][o] = sum_{m2} UL[l][m2] * V[m2][o]
// grid (BHc, 16), 256 thr. Wave w owns l rows [64w, 64w+64) of a 256-l block.
// Vt staged in LDS [o][136]. r13: epilogue via per-wave LDS transpose
// ([16][72] f32, 16B-aligned rows) -> fully-coalesced float4 stores.
// ---------------------------------------------------------------------------
__global__ __launch_bounds__(256) void inv_k(const _Float16* __restrict__ UL,
                                             const _Float16* __restrict__ Vt,
                                             float* __restrict__ out) {
    __shared__ __align__(16) char smem[4 * 1152 * 4];   // 18.4KB
    _Float16* vs = (_Float16*)smem;            // [64][136] staging view
    int bh = blockIdx.x, lb = blockIdx.y;
    int tid = threadIdx.x, lane = tid & 63, w = tid >> 6;
    int lo16 = lane & 15, kg = lane >> 4;
    #pragma unroll
    for (int i = 0; i < 4; ++i) {
        int f = i * 256 + tid;                 // 1024 chunks of 8 f16
        int row = f >> 4, seg = f & 15;
        uint4 t4 = *(const uint4*)(Vt + (size_t)bh * 8192 + row * 128 + seg * 8);
        *(uint4*)&vs[row * 136 + seg * 8] = t4;
    }
    __syncthreads();
    int lt0 = lb * 256 + w * 64;
    const _Float16* up = UL + (size_t)(lt0 + lo16) * 128 + kg * 8;
    f32x4 acc[4][4] = {};
    #pragma unroll
    for (int ks = 0; ks < 4; ++ks) {
        half8 Af[4];
        #pragma unroll
        for (int a = 0; a < 4; ++a)
            Af[a] = *(const half8*)(up + (size_t)a * 16 * 128 + ks * 32);
        #pragma unroll
        for (int j = 0; j < 4; ++j) {
            half8 Bf = *(const half8*)&vs[(16 * j + lo16) * 136 + ks * 32 + kg * 8];
            #pragma unroll
            for (int a = 0; a < 4; ++a)
                acc[a][j] = __builtin_amdgcn_mfma_f32_16x16x32_f16(Af[a], Bf, acc[a][j], 0, 0, 0);
        }
    }
    __syncthreads();                           // all waves done reading vs
    float* scr = (float*)smem + w * 1152;      // per-wave [16][72] scratch
    float* op = out + ((size_t)bh * Lc + lt0) * Ec;
    int rr = lane >> 4, cc = lane & 15;
    #pragma unroll
    for (int a = 0; a < 4; ++a) {
        #pragma unroll
        for (int j = 0; j < 4; ++j)
            #pragma unroll
            for (int r = 0; r < 4; ++r)
                scr[(kg * 4 + r) * 72 + 16 * j + lo16] = acc[a][j][r];
        // same-wave DS ordering guarantees write->read consistency
        #pragma unroll
        for (int g = 0; g < 4; ++g) {
            int row = g * 4 + rr;
            float4 v = *(float4*)&scr[row * 72 + cc * 4];
            *(float4*)(op + (size_t)(a * 16 + row) * Ec + cc * 4) = v;
        }
    }
}

// ---------------------------------------------------------------------------
extern "C" void kernel_launch(void* const* d_in, const int* in_sizes, int n_in,
                              void* d_out, int out_size, void* d_ws, size_t ws_size,
                              hipStream_t stream) {
    const float* x   = (const float*)d_in[0];
    const float* wgt = (const float*)d_in[1];
    const int*   idx = (const int*)d_in[2];
    float* out = (float*)d_out;

    // workspace layout: selP (nch*4MB) | Tt (1MB) | UL (1MB) | Vt (2MB)
    size_t need8 = (size_t)8 * BHc * 8192 * 4 + (2ull * 128 * Lc + (size_t)BHc * 8192) * 2;
    int nch = (ws_size >= need8) ? 8 : 4;

    char* ws = (char*)d_ws;
    float*    selP = (float*)ws;
    _Float16* Tt   = (_Float16*)(ws + (size_t)nch * BHc * 8192 * 4);
    _Float16* UL   = Tt + (size_t)128 * Lc;
    _Float16* Vt   = UL + (size_t)Lc * 128;

    twid_k<<<2048, 256, 0, stream>>>(idx, Tt, UL);
    if (nch == 8)
        fwd_k<8><<<dim3(BHc, 8), 256, 0, stream>>>(x, Tt, selP);
    else
        fwd_k<4><<<dim3(BHc, 4), 256, 0, stream>>>(x, Tt, selP);
    mix_k<<<dim3(BHc, 4), 256, 0, stream>>>(selP, wgt, idx, Vt, nch);
    inv_k<<<dim3(BHc, 16), 256, 0, stream>>>(UL, Vt, out);
}

// Round 14
// 126.972 us; speedup vs baseline: 1.5703x; 1.0290x over previous
//
#include <hip/hip_runtime.h>

using half8 = __attribute__((ext_vector_type(8))) _Float16;
using f32x4 = __attribute__((ext_vector_type(4))) float;

#define Lc 4096
#define Ec 64
#define Mc 64
#define BHc 128

// 2*pi/4096
#define TWO_PI_OVER_L 1.5339807878856412e-3f

// ---------------------------------------------------------------------------
// Twiddle tables, both coalesced. Native __sinf/__cosf (v_sin/v_cos) —
// accuracy ~2^-21, far below f16 storage quantization (2^-11). [kept from r13]
//   Tt[m2][l]  f16, m2 in [0,128): rows 0..63 = cos(th), rows 64..127 = -sin(th)
//   UL[l][m2]  f16: cols 0..63 = cos(th), cols 64..127 = +sin(th)
// ---------------------------------------------------------------------------
__global__ __launch_bounds__(256) void twid_k(const int* __restrict__ idx,
                                              _Float16* __restrict__ Tt,
                                              _Float16* __restrict__ UL) {
    int id = blockIdx.x * 256 + threadIdx.x;   // 0 .. 524287
    {   // UL pass: l = id>>7, m2 = id&127  (coalesced in m2)
        int l = id >> 7, m2 = id & 127, m = m2 & 63;
        int k = idx[m];
        int ph = (k * l) & (Lc - 1);
        float ang = (float)ph * TWO_PI_OVER_L;
        UL[id] = (_Float16)((m2 >= 64) ? __sinf(ang) : __cosf(ang));
    }
    {   // Tt pass: m2 = id>>12, l = id&4095  (coalesced in l)
        int m2 = id >> 12, l = id & 4095, m = m2 & 63;
        int k = idx[m];
        int ph = (k * l) & (Lc - 1);
        float ang = (float)ph * TWO_PI_OVER_L;
        Tt[id] = (_Float16)((m2 >= 64) ? -__sinf(ang) : __cosf(ang));
    }
}

// ---------------------------------------------------------------------------
// Forward: selP[ch][bh][m2=128][e=64] = sum_{l in chunk} Tt[m2][l] * x[bh][l][e]
// grid (BHc, NCH), 256 thr (4 waves). Wave w owns m2 rows [32w, 32w+32).
// r8 pipeline: double-buffered LDS (1 barrier/tile) + 2-tile-ahead register
// prefetch. Measured (r11 probe): ~30 us ≈ traffic floor. UNCHANGED.
// xs layout: [e][l] f16, row = 128B, byte ^= ((e&7)<<4).
// ---------------------------------------------------------------------------
#define LOADT(SET, S) do{                                                     \
    const float* g0_ = xp + (size_t)((S) * 64 + 2 * lp) * Ec;                 \
    const float* g1_ = xp + (size_t)((S) * 64 + 2 * lp + 32) * Ec;            \
    ra[SET][0] = *(const float4*)g0_;  rb[SET][0] = *(const float4*)(g0_ + Ec);\
    ra[SET][1] = *(const float4*)g1_;  rb[SET][1] = *(const float4*)(g1_ + Ec);\
}while(0)

#define PACKT(SET, BUF) do{                                                   \
    _Pragma("unroll")                                                         \
    for (int i_ = 0; i_ < 2; ++i_) {                                          \
        const float* pa_ = (const float*)&ra[SET][i_];                        \
        const float* pb_ = (const float*)&rb[SET][i_];                        \
        unsigned int pk_[4];                                                  \
        _Pragma("unroll")                                                     \
        for (int j_ = 0; j_ < 4; ++j_) {                                      \
            unsigned short ua_ = __builtin_bit_cast(unsigned short, (_Float16)pa_[j_]); \
            unsigned short ub_ = __builtin_bit_cast(unsigned short, (_Float16)pb_[j_]); \
            pk_[j_] = ua_ | ((unsigned int)ub_ << 16);                        \
        }                                                                     \
        _Pragma("unroll")                                                     \
        for (int j_ = 0; j_ < 4; ++j_) {                                      \
            int jr_ = (j_ + col4) & 3;                                        \
            int e_  = col4 * 4 + jr_;                                         \
            int byt_ = (e_ * 128 + lp * 4 + i_ * 64) ^ ((e_ & 7) << 4);       \
            *(unsigned int*)((char*)xs[BUF] + byt_) = pk_[jr_];               \
        }                                                                     \
    }                                                                         \
}while(0)

#define MFMA_STEP(S, BUF) do{                                                 \
    _Pragma("unroll")                                                         \
    for (int ks_ = 0; ks_ < 2; ++ks_) {                                       \
        half8 A0_ = *(const half8*)(tp + (S) * 64 + ks_ * 32);                \
        half8 A1_ = *(const half8*)(tp + (size_t)16 * Lc + (S) * 64 + ks_ * 32); \
        _Pragma("unroll")                                                     \
        for (int j_ = 0; j_ < 4; ++j_) {                                      \
            int rbyt_ = ((16 * j_ + lo16) * 128 + ks_ * 64 + kg * 16) ^ ((lo16 & 7) << 4); \
            half8 Bv_ = *(const half8*)((const char*)xs[BUF] + rbyt_);        \
            acc[0][j_] = __builtin_amdgcn_mfma_f32_16x16x32_f16(A0_, Bv_, acc[0][j_], 0, 0, 0); \
            acc[1][j_] = __builtin_amdgcn_mfma_f32_16x16x32_f16(A1_, Bv_, acc[1][j_], 0, 0, 0); \
        }                                                                     \
    }                                                                         \
}while(0)

template<int NCH>
__global__ __launch_bounds__(256) void fwd_k(const float* __restrict__ x,
                                             const _Float16* __restrict__ Tt,
                                             float* __restrict__ selP) {
    constexpr int CH = Lc / NCH;
    constexpr int NT = CH / 64;                // 8 at NCH=8 (even)
    __shared__ _Float16 xs[2][64 * 64];        // 2 x 8KB
    int bh = blockIdx.x, ch = blockIdx.y;
    int tid = threadIdx.x;
    int lane = tid & 63, w = tid >> 6;
    int lo16 = lane & 15, kg = lane >> 4;
    int col4 = tid & 15, lp = tid >> 4;        // staging: e4=col4*4, row-pair lp

    const float* xp = x + ((size_t)bh * Lc + (size_t)ch * CH) * Ec + col4 * 4;
    const _Float16* tp = Tt + (size_t)(w * 32 + lo16) * Lc + ch * CH + kg * 8;

    float4 ra[2][2], rb[2][2];                 // [regset][i]
    LOADT(0, 0);                               // tile 0 -> set0
    LOADT(1, 1);                               // tile 1 -> set1
    PACKT(0, 0);                               // tile 0 -> buf0
    __syncthreads();

    f32x4 acc[2][4] = {};
    for (int t = 0; t < NT / 2; ++t) {
        int s0 = 2 * t, s1 = 2 * t + 1;
        if (s0 + 2 < NT) LOADT(0, s0 + 2);
        PACKT(1, 1);
        MFMA_STEP(s0, 0);
        __syncthreads();
        if (s1 + 2 < NT) LOADT(1, s1 + 2);
        if (s1 + 1 < NT) PACKT(0, 0);
        MFMA_STEP(s1, 1);
        __syncthreads();
    }

    float* op = selP + (size_t)(ch * BHc + bh) * (128 * Ec);
    #pragma unroll
    for (int a = 0; a < 2; ++a)
        #pragma unroll
        for (int j = 0; j < 4; ++j)
            #pragma unroll
            for (int r = 0; r < 4; ++r) {
                int m2 = w * 32 + a * 16 + kg * 4 + r;
                int e  = 16 * j + lo16;
                op[m2 * Ec + e] = acc[a][j][r];
            }
}

// ---------------------------------------------------------------------------
// Mix v3: reduce K-partials, complex weight einsum, fold irfft scale.
// grid (BHc, 4 mh) — split by m ONLY, selP read exactly once. [kept from r13]
// Block: all 64 o x 16 m. Wave w = m-group -> sel_s reads are wave-uniform
// broadcasts. Vt[bh][o=64][m2=128] f16: cols 0..63 = s*Re, 64..127 = -s*Im.
// ---------------------------------------------------------------------------
__global__ __launch_bounds__(256) void mix_k(const float* __restrict__ selP,
                                             const float* __restrict__ wgt,
                                             const int* __restrict__ idx,
                                             _Float16* __restrict__ Vt, int nch) {
    __shared__ float sel_s[32 * 65];           // 16 Re rows + 16 Im rows; 8.3KB
    int bh = blockIdx.x, mh = blockIdx.y;      // mh 0..3
    int tid = threadIdx.x;
    #pragma unroll
    for (int i = 0; i < 2; ++i) {
        int f4 = i * 256 + tid;                // 512 float4 = 32 rows x 64 e
        int lr = f4 >> 4, e4 = (f4 & 15) * 4;
        int m2 = (lr < 16) ? (mh * 16 + lr) : (64 + mh * 16 + (lr - 16));
        float4 a = make_float4(0.f, 0.f, 0.f, 0.f);
        for (int chn = 0; chn < nch; ++chn) {
            float4 v = *(const float4*)(selP + (size_t)(chn * BHc + bh) * 8192
                                             + (size_t)m2 * Ec + e4);
            a.x += v.x; a.y += v.y; a.z += v.z; a.w += v.w;
        }
        float* dst = &sel_s[lr * 65 + e4];
        dst[0] = a.x; dst[1] = a.y; dst[2] = a.z; dst[3] = a.w;
    }
    __syncthreads();
    int o = tid & 63, mg = tid >> 6;           // wave = m-group
    int mloc = mg * 4;                         // local m base (4 m per thread)
    int m0 = mh * 16 + mloc;                   // global m base
    float rR[4] = {0}, rI[4] = {0};
    #pragma unroll 4
    for (int e = 0; e < Ec; ++e) {
        const float4* wp = (const float4*)&wgt[(((size_t)e * Ec + o) * Mc + m0) * 2];
        float4 w0 = wp[0], w1 = wp[1];         // (R,I) for m0..m0+3
        float sr0 = sel_s[(mloc + 0) * 65 + e], si0 = sel_s[(16 + mloc + 0) * 65 + e];
        float sr1 = sel_s[(mloc + 1) * 65 + e], si1 = sel_s[(16 + mloc + 1) * 65 + e];
        float sr2 = sel_s[(mloc + 2) * 65 + e], si2 = sel_s[(16 + mloc + 2) * 65 + e];
        float sr3 = sel_s[(mloc + 3) * 65 + e], si3 = sel_s[(16 + mloc + 3) * 65 + e];
        rR[0] += sr0 * w0.x - si0 * w0.y;  rI[0] += sr0 * w0.y + si0 * w0.x;
        rR[1] += sr1 * w0.z - si1 * w0.w;  rI[1] += sr1 * w0.w + si1 * w0.z;
        rR[2] += sr2 * w1.x - si2 * w1.y;  rI[2] += sr2 * w1.y + si2 * w1.x;
        rR[3] += sr3 * w1.z - si3 * w1.w;  rI[3] += sr3 * w1.w + si3 * w1.z;
    }
    _Float16* vp = Vt + ((size_t)bh * 64 + o) * 128;
    #pragma unroll
    for (int p = 0; p < 2; ++p) {
        float s0 = (idx[m0 + 2 * p] == 0 ? 1.0f : 2.0f) / (float)Lc;
        float s1 = (idx[m0 + 2 * p + 1] == 0 ? 1.0f : 2.0f) / (float)Lc;
        unsigned short r0 = __builtin_bit_cast(unsigned short, (_Float16)(rR[2 * p] * s0));
        unsigned short r1 = __builtin_bit_cast(unsigned short, (_Float16)(rR[2 * p + 1] * s1));
        unsigned short i0 = __builtin_bit_cast(unsigned short, (_Float16)(-rI[2 * p] * s0));
        unsigned short i1 = __builtin_bit_cast(unsigned short, (_Float16)(-rI[2 * p + 1] * s1));
        *(unsigned int*)&vp[m0 + 2 * p]      = r0 | ((unsigned int)r1 << 16);
        *(unsigned int*)&vp[64 + m0 + 2 * p] = i0 | ((unsigned int)i1 << 16);
    }
}

// ---------------------------------------------------------------------------
// Inverse: out[bh][l][o] = sum_{m2} UL[l][m2] * V[m2][o]
// grid (BHc, 16), 256 thr. Wave w owns l rows [64w, 64w+64) of a 256-l block.
// Vt staged in LDS [o][136] (17-bank stride). r14: REVERTED to r10 epilogue —
// direct stores (lo16 groups already write contiguous 64B segments; the r13
// LDS-transpose epilogue was pure overhead).
// ---------------------------------------------------------------------------
__global__ __launch_bounds__(256) void inv_k(const _Float16* __restrict__ UL,
                                             const _Float16* __restrict__ Vt,
                                             float* __restrict__ out) {
    __shared__ _Float16 vs[64 * 136];          // 17.4KB
    int bh = blockIdx.x, lb = blockIdx.y;
    int tid = threadIdx.x, lane = tid & 63, w = tid >> 6;
    int lo16 = lane & 15, kg = lane >> 4;
    #pragma unroll
    for (int i = 0; i < 4; ++i) {
        int f = i * 256 + tid;                 // 1024 chunks of 8 f16
        int row = f >> 4, seg = f & 15;
        uint4 t4 = *(const uint4*)(Vt + (size_t)bh * 8192 + row * 128 + seg * 8);
        *(uint4*)&vs[row * 136 + seg * 8] = t4;
    }
    __syncthreads();
    int lt0 = lb * 256 + w * 64;
    const _Float16* up = UL + (size_t)(lt0 + lo16) * 128 + kg * 8;
    f32x4 acc[4][4] = {};
    #pragma unroll
    for (int ks = 0; ks < 4; ++ks) {
        half8 Af[4];
        #pragma unroll
        for (int a = 0; a < 4; ++a)
            Af[a] = *(const half8*)(up + (size_t)a * 16 * 128 + ks * 32);
        #pragma unroll
        for (int j = 0; j < 4; ++j) {
            half8 Bf = *(const half8*)&vs[(16 * j + lo16) * 136 + ks * 32 + kg * 8];
            #pragma unroll
            for (int a = 0; a < 4; ++a)
                acc[a][j] = __builtin_amdgcn_mfma_f32_16x16x32_f16(Af[a], Bf, acc[a][j], 0, 0, 0);
        }
    }
    float* op = out + ((size_t)bh * Lc + lt0) * Ec;
    #pragma unroll
    for (int a = 0; a < 4; ++a)
        #pragma unroll
        for (int j = 0; j < 4; ++j)
            #pragma unroll
            for (int r = 0; r < 4; ++r) {
                int ll = a * 16 + kg * 4 + r;
                int o  = 16 * j + lo16;
                op[ll * Ec + o] = acc[a][j][r];
            }
}

// ---------------------------------------------------------------------------
extern "C" void kernel_launch(void* const* d_in, const int* in_sizes, int n_in,
                              void* d_out, int out_size, void* d_ws, size_t ws_size,
                              hipStream_t stream) {
    const float* x   = (const float*)d_in[0];
    const float* wgt = (const float*)d_in[1];
    const int*   idx = (const int*)d_in[2];
    float* out = (float*)d_out;

    // workspace layout: selP (nch*4MB) | Tt (1MB) | UL (1MB) | Vt (2MB)
    size_t need8 = (size_t)8 * BHc * 8192 * 4 + (2ull * 128 * Lc + (size_t)BHc * 8192) * 2;
    int nch = (ws_size >= need8) ? 8 : 4;

    char* ws = (char*)d_ws;
    float*    selP = (float*)ws;
    _Float16* Tt   = (_Float16*)(ws + (size_t)nch * BHc * 8192 * 4);
    _Float16* UL   = Tt + (size_t)128 * Lc;
    _Float16* Vt   = UL + (size_t)Lc * 128;

    twid_k<<<2048, 256, 0, stream>>>(idx, Tt, UL);
    if (nch == 8)
        fwd_k<8><<<dim3(BHc, 8), 256, 0, stream>>>(x, Tt, selP);
    else
        fwd_k<4><<<dim3(BHc, 4), 256, 0, stream>>>(x, Tt, selP);
    mix_k<<<dim3(BHc, 4), 256, 0, stream>>>(selP, wgt, idx, Vt, nch);
    inv_k<<<dim3(BHc, 16), 256, 0, stream>>>(UL, Vt, out);
}

// Round 15
// 115.851 us; speedup vs baseline: 1.7210x; 1.0960x over previous
//
#include <hip/hip_runtime.h>

using half8 = __attribute__((ext_vector_type(8))) _Float16;
using f32x4 = __attribute__((ext_vector_type(4))) float;
using u16x4 = __attribute__((ext_vector_type(4))) unsigned short;

#define Lc 4096
#define Ec 64
#define Mc 64
#define BHc 128

// 2*pi/4096
#define TWO_PI_OVER_L 1.5339807878856412e-3f

// ---------------------------------------------------------------------------
// Twiddle tables, both coalesced (r10 version, libm sincosf):
//   Tt[m2][l]  f16, m2 in [0,128): rows 0..63 = cos(th), rows 64..127 = -sin(th)
//   UL[l][m2]  f16: cols 0..63 = cos(th), cols 64..127 = +sin(th)
// ---------------------------------------------------------------------------
__global__ __launch_bounds__(256) void twid_k(const int* __restrict__ idx,
                                              _Float16* __restrict__ Tt,
                                              _Float16* __restrict__ UL) {
    int id = blockIdx.x * 256 + threadIdx.x;   // 0 .. 524287
    {   // UL pass: l = id>>7, m2 = id&127  (coalesced in m2)
        int l = id >> 7, m2 = id & 127, m = m2 & 63;
        int k = idx[m];
        int ph = (k * l) & (Lc - 1);
        float s, c;
        sincosf((float)ph * TWO_PI_OVER_L, &s, &c);
        UL[id] = (_Float16)((m2 >= 64) ? s : c);
    }
    {   // Tt pass: m2 = id>>12, l = id&4095  (coalesced in l)
        int m2 = id >> 12, l = id & 4095, m = m2 & 63;
        int k = idx[m];
        int ph = (k * l) & (Lc - 1);
        float s, c;
        sincosf((float)ph * TWO_PI_OVER_L, &s, &c);
        Tt[id] = (_Float16)((m2 >= 64) ? -s : c);
    }
}

// ---------------------------------------------------------------------------
// Forward: selP[ch][bh][m2=128][e=64] (f16, r15) = sum_l Tt[m2][l]*x[bh][l][e]
// grid (BHc, NCH), 256 thr (4 waves). Wave w owns m2 rows [32w, 32w+32).
// r8 pipeline: double-buffered LDS (1 barrier/tile) + 2-tile-ahead register
// prefetch. Measured (r11 probe): ~30 us ≈ traffic floor.
// r15 change: selP stored f16 (halves fwd-write + mix-read traffic).
// xs layout: [e][l] f16, row = 128B, byte ^= ((e&7)<<4).
// ---------------------------------------------------------------------------
#define LOADT(SET, S) do{                                                     \
    const float* g0_ = xp + (size_t)((S) * 64 + 2 * lp) * Ec;                 \
    const float* g1_ = xp + (size_t)((S) * 64 + 2 * lp + 32) * Ec;            \
    ra[SET][0] = *(const float4*)g0_;  rb[SET][0] = *(const float4*)(g0_ + Ec);\
    ra[SET][1] = *(const float4*)g1_;  rb[SET][1] = *(const float4*)(g1_ + Ec);\
}while(0)

#define PACKT(SET, BUF) do{                                                   \
    _Pragma("unroll")                                                         \
    for (int i_ = 0; i_ < 2; ++i_) {                                          \
        const float* pa_ = (const float*)&ra[SET][i_];                        \
        const float* pb_ = (const float*)&rb[SET][i_];                        \
        unsigned int pk_[4];                                                  \
        _Pragma("unroll")                                                     \
        for (int j_ = 0; j_ < 4; ++j_) {                                      \
            unsigned short ua_ = __builtin_bit_cast(unsigned short, (_Float16)pa_[j_]); \
            unsigned short ub_ = __builtin_bit_cast(unsigned short, (_Float16)pb_[j_]); \
            pk_[j_] = ua_ | ((unsigned int)ub_ << 16);                        \
        }                                                                     \
        _Pragma("unroll")                                                     \
        for (int j_ = 0; j_ < 4; ++j_) {                                      \
            int jr_ = (j_ + col4) & 3;                                        \
            int e_  = col4 * 4 + jr_;                                         \
            int byt_ = (e_ * 128 + lp * 4 + i_ * 64) ^ ((e_ & 7) << 4);       \
            *(unsigned int*)((char*)xs[BUF] + byt_) = pk_[jr_];               \
        }                                                                     \
    }                                                                         \
}while(0)

#define MFMA_STEP(S, BUF) do{                                                 \
    _Pragma("unroll")                                                         \
    for (int ks_ = 0; ks_ < 2; ++ks_) {                                       \
        half8 A0_ = *(const half8*)(tp + (S) * 64 + ks_ * 32);                \
        half8 A1_ = *(const half8*)(tp + (size_t)16 * Lc + (S) * 64 + ks_ * 32); \
        _Pragma("unroll")                                                     \
        for (int j_ = 0; j_ < 4; ++j_) {                                      \
            int rbyt_ = ((16 * j_ + lo16) * 128 + ks_ * 64 + kg * 16) ^ ((lo16 & 7) << 4); \
            half8 Bv_ = *(const half8*)((const char*)xs[BUF] + rbyt_);        \
            acc[0][j_] = __builtin_amdgcn_mfma_f32_16x16x32_f16(A0_, Bv_, acc[0][j_], 0, 0, 0); \
            acc[1][j_] = __builtin_amdgcn_mfma_f32_16x16x32_f16(A1_, Bv_, acc[1][j_], 0, 0, 0); \
        }                                                                     \
    }                                                                         \
}while(0)

template<int NCH>
__global__ __launch_bounds__(256) void fwd_k(const float* __restrict__ x,
                                             const _Float16* __restrict__ Tt,
                                             _Float16* __restrict__ selP) {
    constexpr int CH = Lc / NCH;
    constexpr int NT = CH / 64;                // 8 at NCH=8 (even)
    __shared__ _Float16 xs[2][64 * 64];        // 2 x 8KB
    int bh = blockIdx.x, ch = blockIdx.y;
    int tid = threadIdx.x;
    int lane = tid & 63, w = tid >> 6;
    int lo16 = lane & 15, kg = lane >> 4;
    int col4 = tid & 15, lp = tid >> 4;        // staging: e4=col4*4, row-pair lp

    const float* xp = x + ((size_t)bh * Lc + (size_t)ch * CH) * Ec + col4 * 4;
    const _Float16* tp = Tt + (size_t)(w * 32 + lo16) * Lc + ch * CH + kg * 8;

    float4 ra[2][2], rb[2][2];                 // [regset][i]
    LOADT(0, 0);                               // tile 0 -> set0
    LOADT(1, 1);                               // tile 1 -> set1
    PACKT(0, 0);                               // tile 0 -> buf0
    __syncthreads();

    f32x4 acc[2][4] = {};
    for (int t = 0; t < NT / 2; ++t) {
        int s0 = 2 * t, s1 = 2 * t + 1;
        if (s0 + 2 < NT) LOADT(0, s0 + 2);
        PACKT(1, 1);
        MFMA_STEP(s0, 0);
        __syncthreads();
        if (s1 + 2 < NT) LOADT(1, s1 + 2);
        if (s1 + 1 < NT) PACKT(0, 0);
        MFMA_STEP(s1, 1);
        __syncthreads();
    }

    _Float16* op = selP + (size_t)(ch * BHc + bh) * (128 * Ec);
    #pragma unroll
    for (int a = 0; a < 2; ++a)
        #pragma unroll
        for (int j = 0; j < 4; ++j)
            #pragma unroll
            for (int r = 0; r < 4; ++r) {
                int m2 = w * 32 + a * 16 + kg * 4 + r;
                int e  = 16 * j + lo16;
                op[m2 * Ec + e] = (_Float16)acc[a][j][r];
            }
}

// ---------------------------------------------------------------------------
// Mix v2 (r10 structure): reduce K-partials (f16, r15), complex weight einsum,
// fold irfft scale. Vt[bh][o=64][m2=128] f16.
// grid (BHc, 2 oh, 2 mh) = 512 blocks, stage 64 selP rows (16.6KB), unroll 8.
// ---------------------------------------------------------------------------
__global__ __launch_bounds__(256) void mix_k(const _Float16* __restrict__ selP,
                                             const float* __restrict__ wgt,
                                             const int* __restrict__ idx,
                                             _Float16* __restrict__ Vt, int nch) {
    __shared__ float sel_s[64 * 65];           // rows 0..31 Re, 32..63 Im; 16.6KB
    int bh = blockIdx.x, oh = blockIdx.y, mh = blockIdx.z;
    int tid = threadIdx.x;
    #pragma unroll
    for (int i = 0; i < 4; ++i) {
        int f4 = i * 256 + tid;                // 1024 chunks of 4 halfs
        int lr = f4 >> 4, e4 = (f4 & 15) * 4;
        int m2 = (lr < 32) ? (mh * 32 + lr) : (64 + mh * 32 + (lr - 32));
        float ax = 0.f, ay = 0.f, az = 0.f, aw = 0.f;
        for (int chn = 0; chn < nch; ++chn) {
            u16x4 v = *(const u16x4*)(selP + (size_t)(chn * BHc + bh) * 8192
                                           + (size_t)m2 * Ec + e4);
            ax += (float)__builtin_bit_cast(_Float16, (unsigned short)v[0]);
            ay += (float)__builtin_bit_cast(_Float16, (unsigned short)v[1]);
            az += (float)__builtin_bit_cast(_Float16, (unsigned short)v[2]);
            aw += (float)__builtin_bit_cast(_Float16, (unsigned short)v[3]);
        }
        float* dst = &sel_s[lr * 65 + e4];
        dst[0] = ax; dst[1] = ay; dst[2] = az; dst[3] = aw;
    }
    __syncthreads();
    int og = tid & 15, mg = tid >> 4;
    int o0 = oh * 32 + og * 2;                 // 2 o per thread
    int m0 = mh * 32 + mg * 2;                 // 2 m per thread (global m)
    int lm = mg * 2;                           // local Re row
    float rR[2][2] = {{0}}, rI[2][2] = {{0}};
    #pragma unroll 8
    for (int e = 0; e < Ec; ++e) {
        float sr0 = sel_s[lm * 65 + e];
        float sr1 = sel_s[(lm + 1) * 65 + e];
        float si0 = sel_s[(32 + lm) * 65 + e];
        float si1 = sel_s[(32 + lm + 1) * 65 + e];
        #pragma unroll
        for (int i = 0; i < 2; ++i) {
            const float4* wp = (const float4*)&wgt[(((size_t)e * Ec + (o0 + i)) * Mc + m0) * 2];
            float4 wv = *wp;   // wR[m0], wI[m0], wR[m0+1], wI[m0+1]
            rR[i][0] += sr0 * wv.x - si0 * wv.y;
            rI[i][0] += sr0 * wv.y + si0 * wv.x;
            rR[i][1] += sr1 * wv.z - si1 * wv.w;
            rI[i][1] += sr1 * wv.w + si1 * wv.z;
        }
    }
    float s0 = (idx[m0] == 0 ? 1.0f : 2.0f) / (float)Lc;
    float s1 = (idx[m0 + 1] == 0 ? 1.0f : 2.0f) / (float)Lc;
    #pragma unroll
    for (int i = 0; i < 2; ++i) {
        _Float16* vp = Vt + ((size_t)bh * 64 + o0 + i) * 128;
        unsigned short r0 = __builtin_bit_cast(unsigned short, (_Float16)(rR[i][0] * s0));
        unsigned short r1 = __builtin_bit_cast(unsigned short, (_Float16)(rR[i][1] * s1));
        unsigned short i0 = __builtin_bit_cast(unsigned short, (_Float16)(-rI[i][0] * s0));
        unsigned short i1 = __builtin_bit_cast(unsigned short, (_Float16)(-rI[i][1] * s1));
        *(unsigned int*)&vp[m0]      = r0 | ((unsigned int)r1 << 16);
        *(unsigned int*)&vp[64 + m0] = i0 | ((unsigned int)i1 << 16);
    }
}

// ---------------------------------------------------------------------------
// Inverse: out[bh][l][o] = sum_{m2} UL[l][m2] * V[m2][o]   (r10 version)
// grid (BHc, 16), 256 thr. Wave w owns l rows [64w, 64w+64) of a 256-l block.
// Vt staged in LDS [o][136] (17-bank stride).
// ---------------------------------------------------------------------------
__global__ __launch_bounds__(256) void inv_k(const _Float16* __restrict__ UL,
                                             const _Float16* __restrict__ Vt,
                                             float* __restrict__ out) {
    __shared__ _Float16 vs[64 * 136];          // 17.4KB
    int bh = blockIdx.x, lb = blockIdx.y;
    int tid = threadIdx.x, lane = tid & 63, w = tid >> 6;
    int lo16 = lane & 15, kg = lane >> 4;
    #pragma unroll
    for (int i = 0; i < 4; ++i) {
        int f = i * 256 + tid;                 // 1024 chunks of 8 f16
        int row = f >> 4, seg = f & 15;
        uint4 t4 = *(const uint4*)(Vt + (size_t)bh * 8192 + row * 128 + seg * 8);
        *(uint4*)&vs[row * 136 + seg * 8] = t4;
    }
    __syncthreads();
    int lt0 = lb * 256 + w * 64;
    const _Float16* up = UL + (size_t)(lt0 + lo16) * 128 + kg * 8;
    f32x4 acc[4][4] = {};
    #pragma unroll
    for (int ks = 0; ks < 4; ++ks) {
        half8 Af[4];
        #pragma unroll
        for (int a = 0; a < 4; ++a)
            Af[a] = *(const half8*)(up + (size_t)a * 16 * 128 + ks * 32);
        #pragma unroll
        for (int j = 0; j < 4; ++j) {
            half8 Bf = *(const half8*)&vs[(16 * j + lo16) * 136 + ks * 32 + kg * 8];
            #pragma unroll
            for (int a = 0; a < 4; ++a)
                acc[a][j] = __builtin_amdgcn_mfma_f32_16x16x32_f16(Af[a], Bf, acc[a][j], 0, 0, 0);
        }
    }
    float* op = out + ((size_t)bh * Lc + lt0) * Ec;
    #pragma unroll
    for (int a = 0; a < 4; ++a)
        #pragma unroll
        for (int j = 0; j < 4; ++j)
            #pragma unroll
            for (int r = 0; r < 4; ++r) {
                int ll = a * 16 + kg * 4 + r;
                int o  = 16 * j + lo16;
                op[ll * Ec + o] = acc[a][j][r];
            }
}

// ---------------------------------------------------------------------------
extern "C" void kernel_launch(void* const* d_in, const int* in_sizes, int n_in,
                              void* d_out, int out_size, void* d_ws, size_t ws_size,
                              hipStream_t stream) {
    const float* x   = (const float*)d_in[0];
    const float* wgt = (const float*)d_in[1];
    const int*   idx = (const int*)d_in[2];
    float* out = (float*)d_out;

    // workspace layout: selP f16 (nch*2MB) | Tt (1MB) | UL (1MB) | Vt (2MB)
    size_t tail  = (2ull * 128 * Lc + (size_t)BHc * 8192) * 2;
    size_t need8 = (size_t)8 * BHc * 8192 * 2 + tail;
    int nch = (ws_size >= need8) ? 8 : 4;

    char* ws = (char*)d_ws;
    _Float16* selP = (_Float16*)ws;
    _Float16* Tt   = (_Float16*)(ws + (size_t)nch * BHc * 8192 * 2);
    _Float16* UL   = Tt + (size_t)128 * Lc;
    _Float16* Vt   = UL + (size_t)Lc * 128;

    twid_k<<<2048, 256, 0, stream>>>(idx, Tt, UL);
    if (nch == 8)
        fwd_k<8><<<dim3(BHc, 8), 256, 0, stream>>>(x, Tt, selP);
    else
        fwd_k<4><<<dim3(BHc, 4), 256, 0, stream>>>(x, Tt, selP);
    mix_k<<<dim3(BHc, 2, 2), 256, 0, stream>>>(selP, wgt, idx, Vt, nch);
    inv_k<<<dim3(BHc, 16), 256, 0, stream>>>(UL, Vt, out);
}

// Round 16
// 115.416 us; speedup vs baseline: 1.7275x; 1.0038x over previous
//
#include <hip/hip_runtime.h>

using half8 = __attribute__((ext_vector_type(8))) _Float16;
using f32x4 = __attribute__((ext_vector_type(4))) float;
using u16x4 = __attribute__((ext_vector_type(4))) unsigned short;

#define Lc 4096
#define Ec 64
#define Mc 64
#define BHc 128

// 2*pi/4096
#define TWO_PI_OVER_L 1.5339807878856412e-3f

// ---------------------------------------------------------------------------
// Twiddle tables, both coalesced. r16: native __sinf/__cosf (v_sin/v_cos),
// accuracy ~2^-21 << f16 storage quantization (validated r13/r14: absmax
// unchanged).
//   Tt[m2][l]  f16, m2 in [0,128): rows 0..63 = cos(th), rows 64..127 = -sin(th)
//   UL[l][m2]  f16: cols 0..63 = cos(th), cols 64..127 = +sin(th)
// ---------------------------------------------------------------------------
__global__ __launch_bounds__(256) void twid_k(const int* __restrict__ idx,
                                              _Float16* __restrict__ Tt,
                                              _Float16* __restrict__ UL) {
    int id = blockIdx.x * 256 + threadIdx.x;   // 0 .. 524287
    {   // UL pass: l = id>>7, m2 = id&127  (coalesced in m2)
        int l = id >> 7, m2 = id & 127, m = m2 & 63;
        int k = idx[m];
        int ph = (k * l) & (Lc - 1);
        float ang = (float)ph * TWO_PI_OVER_L;
        UL[id] = (_Float16)((m2 >= 64) ? __sinf(ang) : __cosf(ang));
    }
    {   // Tt pass: m2 = id>>12, l = id&4095  (coalesced in l)
        int m2 = id >> 12, l = id & 4095, m = m2 & 63;
        int k = idx[m];
        int ph = (k * l) & (Lc - 1);
        float ang = (float)ph * TWO_PI_OVER_L;
        Tt[id] = (_Float16)((m2 >= 64) ? -__sinf(ang) : __cosf(ang));
    }
}

// ---------------------------------------------------------------------------
// Forward: selP[ch][bh][m2=128][e=64] (f16) = sum_l Tt[m2][l]*x[bh][l][e]
// grid (BHc, NCH), 256 thr (4 waves). Wave w owns m2 rows [32w, 32w+32).
// r8 pipeline: double-buffered LDS (1 barrier/tile) + 2-tile-ahead register
// prefetch. Measured ~30 us ≈ 1.25x traffic floor. UNCHANGED from r15.
// xs layout: [e][l] f16, row = 128B, byte ^= ((e&7)<<4).
// ---------------------------------------------------------------------------
#define LOADT(SET, S) do{                                                     \
    const float* g0_ = xp + (size_t)((S) * 64 + 2 * lp) * Ec;                 \
    const float* g1_ = xp + (size_t)((S) * 64 + 2 * lp + 32) * Ec;            \
    ra[SET][0] = *(const float4*)g0_;  rb[SET][0] = *(const float4*)(g0_ + Ec);\
    ra[SET][1] = *(const float4*)g1_;  rb[SET][1] = *(const float4*)(g1_ + Ec);\
}while(0)

#define PACKT(SET, BUF) do{                                                   \
    _Pragma("unroll")                                                         \
    for (int i_ = 0; i_ < 2; ++i_) {                                          \
        const float* pa_ = (const float*)&ra[SET][i_];                        \
        const float* pb_ = (const float*)&rb[SET][i_];                        \
        unsigned int pk_[4];                                                  \
        _Pragma("unroll")                                                     \
        for (int j_ = 0; j_ < 4; ++j_) {                                      \
            unsigned short ua_ = __builtin_bit_cast(unsigned short, (_Float16)pa_[j_]); \
            unsigned short ub_ = __builtin_bit_cast(unsigned short, (_Float16)pb_[j_]); \
            pk_[j_] = ua_ | ((unsigned int)ub_ << 16);                        \
        }                                                                     \
        _Pragma("unroll")                                                     \
        for (int j_ = 0; j_ < 4; ++j_) {                                      \
            int jr_ = (j_ + col4) & 3;                                        \
            int e_  = col4 * 4 + jr_;                                         \
            int byt_ = (e_ * 128 + lp * 4 + i_ * 64) ^ ((e_ & 7) << 4);       \
            *(unsigned int*)((char*)xs[BUF] + byt_) = pk_[jr_];               \
        }                                                                     \
    }                                                                         \
}while(0)

#define MFMA_STEP(S, BUF) do{                                                 \
    _Pragma("unroll")                                                         \
    for (int ks_ = 0; ks_ < 2; ++ks_) {                                       \
        half8 A0_ = *(const half8*)(tp + (S) * 64 + ks_ * 32);                \
        half8 A1_ = *(const half8*)(tp + (size_t)16 * Lc + (S) * 64 + ks_ * 32); \
        _Pragma("unroll")                                                     \
        for (int j_ = 0; j_ < 4; ++j_) {                                      \
            int rbyt_ = ((16 * j_ + lo16) * 128 + ks_ * 64 + kg * 16) ^ ((lo16 & 7) << 4); \
            half8 Bv_ = *(const half8*)((const char*)xs[BUF] + rbyt_);        \
            acc[0][j_] = __builtin_amdgcn_mfma_f32_16x16x32_f16(A0_, Bv_, acc[0][j_], 0, 0, 0); \
            acc[1][j_] = __builtin_amdgcn_mfma_f32_16x16x32_f16(A1_, Bv_, acc[1][j_], 0, 0, 0); \
        }                                                                     \
    }                                                                         \
}while(0)

template<int NCH>
__global__ __launch_bounds__(256) void fwd_k(const float* __restrict__ x,
                                             const _Float16* __restrict__ Tt,
                                             _Float16* __restrict__ selP) {
    constexpr int CH = Lc / NCH;
    constexpr int NT = CH / 64;                // 8 at NCH=8 (even)
    __shared__ _Float16 xs[2][64 * 64];        // 2 x 8KB
    int bh = blockIdx.x, ch = blockIdx.y;
    int tid = threadIdx.x;
    int lane = tid & 63, w = tid >> 6;
    int lo16 = lane & 15, kg = lane >> 4;
    int col4 = tid & 15, lp = tid >> 4;        // staging: e4=col4*4, row-pair lp

    const float* xp = x + ((size_t)bh * Lc + (size_t)ch * CH) * Ec + col4 * 4;
    const _Float16* tp = Tt + (size_t)(w * 32 + lo16) * Lc + ch * CH + kg * 8;

    float4 ra[2][2], rb[2][2];                 // [regset][i]
    LOADT(0, 0);                               // tile 0 -> set0
    LOADT(1, 1);                               // tile 1 -> set1
    PACKT(0, 0);                               // tile 0 -> buf0
    __syncthreads();

    f32x4 acc[2][4] = {};
    for (int t = 0; t < NT / 2; ++t) {
        int s0 = 2 * t, s1 = 2 * t + 1;
        if (s0 + 2 < NT) LOADT(0, s0 + 2);
        PACKT(1, 1);
        MFMA_STEP(s0, 0);
        __syncthreads();
        if (s1 + 2 < NT) LOADT(1, s1 + 2);
        if (s1 + 1 < NT) PACKT(0, 0);
        MFMA_STEP(s1, 1);
        __syncthreads();
    }

    _Float16* op = selP + (size_t)(ch * BHc + bh) * (128 * Ec);
    #pragma unroll
    for (int a = 0; a < 2; ++a)
        #pragma unroll
        for (int j = 0; j < 4; ++j)
            #pragma unroll
            for (int r = 0; r < 4; ++r) {
                int m2 = w * 32 + a * 16 + kg * 4 + r;
                int e  = 16 * j + lo16;
                op[m2 * Ec + e] = (_Float16)acc[a][j][r];
            }
}

// ---------------------------------------------------------------------------
// Mix v2-merged (r16): same inner math and wgt access pattern as r15's v2,
// but the two o-halves live in ONE 512-thread block -> selP staged/read ONCE
// (was 2x). grid (BHc, 2 mh), 512 thr. Thread owns 2 o x 2 m
// (og=tid&31 -> o0=og*2; mg=tid>>5 -> m0=mh*32+mg*2).
// Vt[bh][o=64][m2=128] f16: cols 0..63 = s*Re, 64..127 = -s*Im.
// ---------------------------------------------------------------------------
__global__ __launch_bounds__(512) void mix_k(const _Float16* __restrict__ selP,
                                             const float* __restrict__ wgt,
                                             const int* __restrict__ idx,
                                             _Float16* __restrict__ Vt, int nch) {
    __shared__ float sel_s[64 * 65];           // rows 0..31 Re, 32..63 Im; 16.6KB
    int bh = blockIdx.x, mh = blockIdx.y;      // mh 0..1
    int tid = threadIdx.x;
    #pragma unroll
    for (int i = 0; i < 2; ++i) {
        int f4 = i * 512 + tid;                // 1024 chunks of 4 halfs
        int lr = f4 >> 4, e4 = (f4 & 15) * 4;
        int m2 = (lr < 32) ? (mh * 32 + lr) : (64 + mh * 32 + (lr - 32));
        float ax = 0.f, ay = 0.f, az = 0.f, aw = 0.f;
        for (int chn = 0; chn < nch; ++chn) {
            u16x4 v = *(const u16x4*)(selP + (size_t)(chn * BHc + bh) * 8192
                                           + (size_t)m2 * Ec + e4);
            ax += (float)__builtin_bit_cast(_Float16, (unsigned short)v[0]);
            ay += (float)__builtin_bit_cast(_Float16, (unsigned short)v[1]);
            az += (float)__builtin_bit_cast(_Float16, (unsigned short)v[2]);
            aw += (float)__builtin_bit_cast(_Float16, (unsigned short)v[3]);
        }
        float* dst = &sel_s[lr * 65 + e4];
        dst[0] = ax; dst[1] = ay; dst[2] = az; dst[3] = aw;
    }
    __syncthreads();
    int og = tid & 31, mg = tid >> 5;
    int o0 = og * 2;                           // 2 o per thread (covers all 64)
    int m0 = mh * 32 + mg * 2;                 // 2 m per thread (global m)
    int lm = mg * 2;                           // local Re row
    float rR[2][2] = {{0}}, rI[2][2] = {{0}};
    #pragma unroll 8
    for (int e = 0; e < Ec; ++e) {
        float sr0 = sel_s[lm * 65 + e];
        float sr1 = sel_s[(lm + 1) * 65 + e];
        float si0 = sel_s[(32 + lm) * 65 + e];
        float si1 = sel_s[(32 + lm + 1) * 65 + e];
        #pragma unroll
        for (int i = 0; i < 2; ++i) {
            const float4* wp = (const float4*)&wgt[(((size_t)e * Ec + (o0 + i)) * Mc + m0) * 2];
            float4 wv = *wp;   // wR[m0], wI[m0], wR[m0+1], wI[m0+1]
            rR[i][0] += sr0 * wv.x - si0 * wv.y;
            rI[i][0] += sr0 * wv.y + si0 * wv.x;
            rR[i][1] += sr1 * wv.z - si1 * wv.w;
            rI[i][1] += sr1 * wv.w + si1 * wv.z;
        }
    }
    float s0 = (idx[m0] == 0 ? 1.0f : 2.0f) / (float)Lc;
    float s1 = (idx[m0 + 1] == 0 ? 1.0f : 2.0f) / (float)Lc;
    #pragma unroll
    for (int i = 0; i < 2; ++i) {
        _Float16* vp = Vt + ((size_t)bh * 64 + o0 + i) * 128;
        unsigned short r0 = __builtin_bit_cast(unsigned short, (_Float16)(rR[i][0] * s0));
        unsigned short r1 = __builtin_bit_cast(unsigned short, (_Float16)(rR[i][1] * s1));
        unsigned short i0 = __builtin_bit_cast(unsigned short, (_Float16)(-rI[i][0] * s0));
        unsigned short i1 = __builtin_bit_cast(unsigned short, (_Float16)(-rI[i][1] * s1));
        *(unsigned int*)&vp[m0]      = r0 | ((unsigned int)r1 << 16);
        *(unsigned int*)&vp[64 + m0] = i0 | ((unsigned int)i1 << 16);
    }
}

// ---------------------------------------------------------------------------
// Inverse: out[bh][l][o] = sum_{m2} UL[l][m2] * V[m2][o]   (r10 version)
// grid (BHc, 16), 256 thr. Wave w owns l rows [64w, 64w+64) of a 256-l block.
// Vt staged in LDS [o][136] (17-bank stride). UNCHANGED from r15.
// ---------------------------------------------------------------------------
__global__ __launch_bounds__(256) void inv_k(const _Float16* __restrict__ UL,
                                             const _Float16* __restrict__ Vt,
                                             float* __restrict__ out) {
    __shared__ _Float16 vs[64 * 136];          // 17.4KB
    int bh = blockIdx.x, lb = blockIdx.y;
    int tid = threadIdx.x, lane = tid & 63, w = tid >> 6;
    int lo16 = lane & 15, kg = lane >> 4;
    #pragma unroll
    for (int i = 0; i < 4; ++i) {
        int f = i * 256 + tid;                 // 1024 chunks of 8 f16
        int row = f >> 4, seg = f & 15;
        uint4 t4 = *(const uint4*)(Vt + (size_t)bh * 8192 + row * 128 + seg * 8);
        *(uint4*)&vs[row * 136 + seg * 8] = t4;
    }
    __syncthreads();
    int lt0 = lb * 256 + w * 64;
    const _Float16* up = UL + (size_t)(lt0 + lo16) * 128 + kg * 8;
    f32x4 acc[4][4] = {};
    #pragma unroll
    for (int ks = 0; ks < 4; ++ks) {
        half8 Af[4];
        #pragma unroll
        for (int a = 0; a < 4; ++a)
            Af[a] = *(const half8*)(up + (size_t)a * 16 * 128 + ks * 32);
        #pragma unroll
        for (int j = 0; j < 4; ++j) {
            half8 Bf = *(const half8*)&vs[(16 * j + lo16) * 136 + ks * 32 + kg * 8];
            #pragma unroll
            for (int a = 0; a < 4; ++a)
                acc[a][j] = __builtin_amdgcn_mfma_f32_16x16x32_f16(Af[a], Bf, acc[a][j], 0, 0, 0);
        }
    }
    float* op = out + ((size_t)bh * Lc + lt0) * Ec;
    #pragma unroll
    for (int a = 0; a < 4; ++a)
        #pragma unroll
        for (int j = 0; j < 4; ++j)
            #pragma unroll
            for (int r = 0; r < 4; ++r) {
                int ll = a * 16 + kg * 4 + r;
                int o  = 16 * j + lo16;
                op[ll * Ec + o] = acc[a][j][r];
            }
}

// ---------------------------------------------------------------------------
extern "C" void kernel_launch(void* const* d_in, const int* in_sizes, int n_in,
                              void* d_out, int out_size, void* d_ws, size_t ws_size,
                              hipStream_t stream) {
    const float* x   = (const float*)d_in[0];
    const float* wgt = (const float*)d_in[1];
    const int*   idx = (const int*)d_in[2];
    float* out = (float*)d_out;

    // workspace layout: selP f16 (nch*2MB) | Tt (1MB) | UL (1MB) | Vt (2MB)
    size_t tail  = (2ull * 128 * Lc + (size_t)BHc * 8192) * 2;
    size_t need8 = (size_t)8 * BHc * 8192 * 2 + tail;
    int nch = (ws_size >= need8) ? 8 : 4;

    char* ws = (char*)d_ws;
    _Float16* selP = (_Float16*)ws;
    _Float16* Tt   = (_Float16*)(ws + (size_t)nch * BHc * 8192 * 2);
    _Float16* UL   = Tt + (size_t)128 * Lc;
    _Float16* Vt   = UL + (size_t)Lc * 128;

    twid_k<<<2048, 256, 0, stream>>>(idx, Tt, UL);
    if (nch == 8)
        fwd_k<8><<<dim3(BHc, 8), 256, 0, stream>>>(x, Tt, selP);
    else
        fwd_k<4><<<dim3(BHc, 4), 256, 0, stream>>>(x, Tt, selP);
    mix_k<<<dim3(BHc, 2), 512, 0, stream>>>(selP, wgt, idx, Vt, nch);
    inv_k<<<dim3(BHc, 16), 256, 0, stream>>>(UL, Vt, out);
}